// Round 12
// baseline (216.087 us; speedup 1.0000x reference)
//
#include <hip/hip_runtime.h>

#define B_ 2
#define S_ 2048
#define E_ 1024
#define H_ 16
#define D_ 64
#define BS_ (B_*S_)
#define PSTR 76   // flash P-lds stride in u16

typedef unsigned short u16;
typedef __attribute__((ext_vector_type(8))) short short8;
typedef __attribute__((ext_vector_type(4))) float floatx4;
typedef __bf16 bf16x8 __attribute__((ext_vector_type(8)));

__device__ __forceinline__ u16 f2bf(float f) {
    unsigned int u = __builtin_bit_cast(unsigned int, f);
    u += 0x7FFFu + ((u >> 16) & 1u);
    return (u16)(u >> 16);
}
__device__ __forceinline__ float bf2f(u16 h) {
    return __builtin_bit_cast(float, (unsigned int)h << 16);
}
__device__ __forceinline__ floatx4 mfma16(short8 a, short8 b, floatx4 c) {
    return __builtin_amdgcn_mfma_f32_16x16x32_bf16(
        __builtin_bit_cast(bf16x8, a), __builtin_bit_cast(bf16x8, b), c, 0, 0, 0);
}
__device__ __forceinline__ void gload_lds16(const void* g, void* l) {
    __builtin_amdgcn_global_load_lds(
        (const __attribute__((address_space(1))) unsigned int*)g,
        (__attribute__((address_space(3))) unsigned int*)l, 16, 0, 0);
}

// ---------------- merged prep kernel (4 roles by block range) ----------------
__global__ __launch_bounds__(256) void prep_kernel(const float* __restrict__ x,
                                                   const float* __restrict__ wq,
                                                   const float* __restrict__ wk,
                                                   const float* __restrict__ wv,
                                                   const float* __restrict__ wo,
                                                   u16* __restrict__ xcat,
                                                   u16* __restrict__ wqt,
                                                   u16* __restrict__ wkt,
                                                   u16* __restrict__ wkres,
                                                   u16* __restrict__ wvt,
                                                   u16* __restrict__ wot,
                                                   float* __restrict__ cost,
                                                   float* __restrict__ sint,
                                                   float* __restrict__ qlast) {
    __shared__ float t[32][33];
    int bx = blockIdx.x;
    int tid = threadIdx.x;
    if (bx < 4096) {
        int i = bx * 256 + tid;
        int row = i >> 8, c4 = (i & 255) * 4;
        float4 v = ((const float4*)x)[i];
        u16 h0 = f2bf(v.x), h1 = f2bf(v.y), h2 = f2bf(v.z), h3 = f2bf(v.w);
        uint2 o;
        o.x = (unsigned)h0 | ((unsigned)h1 << 16);
        o.y = (unsigned)h2 | ((unsigned)h3 << 16);
        *(uint2*)&xcat[(size_t)row * 2048 + c4] = o;
        u16 l0 = f2bf(v.x - bf2f(h0)), l1 = f2bf(v.y - bf2f(h1));
        u16 l2 = f2bf(v.z - bf2f(h2)), l3 = f2bf(v.w - bf2f(h3));
        uint2 ol;
        ol.x = (unsigned)l0 | ((unsigned)l1 << 16);
        ol.y = (unsigned)l2 | ((unsigned)l3 << 16);
        *(uint2*)&xcat[(size_t)row * 2048 + 1024 + c4] = ol;
    } else if (bx < 8192) {
        int sub = bx - 4096;
        int which = sub >> 10, s2 = sub & 1023;
        const float* W = which == 0 ? wq : which == 1 ? wk : which == 2 ? wv : wo;
        u16* Wt = which == 0 ? wqt : which == 1 ? wkt : which == 2 ? wvt : wot;
        int tk = (s2 >> 5) * 32, tn = (s2 & 31) * 32;
        int tx = tid & 31, ty = tid >> 5;   // 32 x 8
        for (int i = 0; i < 32; i += 8)
            t[ty + i][tx] = W[(size_t)(tk + ty + i) * E_ + tn + tx];
        __syncthreads();
        for (int i = 0; i < 32; i += 8) {
            float v = t[tx][ty + i];
            u16 hi = f2bf(v);
            Wt[(size_t)(tn + ty + i) * E_ + tk + tx] = hi;
            if (which == 1) {
                wkres[(size_t)(tn + ty + i) * 2048 + tk + tx] = f2bf(v - bf2f(hi));
                wkres[(size_t)(tn + ty + i) * 2048 + 1024 + tk + tx] = hi;
            }
        }
    } else if (bx < 8448) {
        int idx = (bx - 8192) * 256 + tid;   // S_*32
        int s = idx >> 5, i = idx & 31;
        float inv = powf(10000.0f, -(float)i / 32.0f);
        float a = (float)s * inv;
        cost[idx] = cosf(a);
        sint[idx] = sinf(a);
    } else {
        float* red = &t[0][0];               // reuse LDS (256 floats)
        int b2 = bx - 8448;
        int b = b2 >> 5, c0 = (b2 & 31) * 32;
        int cl = tid & 31, kc = tid >> 5;
        const float* xr = &x[((size_t)b * S_ + (S_ - 1)) * E_ + kc * 128];
        const float* wp = &wq[(size_t)(kc * 128) * E_ + c0 + cl];
        float acc = 0.f;
#pragma unroll 4
        for (int e = 0; e < 128; ++e) acc = fmaf(xr[e], wp[(size_t)e * E_], acc);
        red[kc * 32 + cl] = acc;
        __syncthreads();
        if (kc == 0) {
            float s = ((red[0 * 32 + cl] + red[1 * 32 + cl]) + (red[2 * 32 + cl] + red[3 * 32 + cl]))
                    + ((red[4 * 32 + cl] + red[5 * 32 + cl]) + (red[6 * 32 + cl] + red[7 * 32 + cl]));
            qlast[(size_t)b * E_ + c0 + cl] = s;
        }
    }
}

// ---------------- GEMM core: 128x128 tile, gload_lds staging, T2 XOR-swizzled LDS ----------------

__device__ __forceinline__ void stage_swz(const u16* __restrict__ src, int row0, int k0,
                                          int stride, u16* lds, int tid) {
    int wv = tid >> 6, ln = tid & 63;
    int swz = (((ln & 7) ^ (ln >> 3)) << 3);   // global col offset (u16) for this lane
    int rr = ln >> 3;
#pragma unroll
    for (int i = 0; i < 4; ++i) {
        int seg = i * 4 + wv;                  // 0..15 ; LDS dest = base + lane*16
        gload_lds16(&src[(size_t)(row0 + seg * 8 + rr) * stride + k0 + swz],
                    (char*)lds + (size_t)seg * 1024);
    }
}

__device__ __forceinline__ void gemm_body(const u16* lA, const u16* lB,
                                          floatx4 (*acc)[4], int lane, int wave) {
    int wm = (wave >> 1) * 64, wn = (wave & 1) * 64;
    int lr = lane & 15, lq = lane >> 4, r7 = lr & 7;
#pragma unroll
    for (int half = 0; half < 2; ++half) {
        int xo = (((half * 4 + lq) ^ r7) << 3);
        short8 afr[4], bfr[4];
#pragma unroll
        for (int mi = 0; mi < 4; ++mi)
            afr[mi] = *(const short8*)&lA[(wm + mi * 16 + lr) * 64 + xo];
#pragma unroll
        for (int ni = 0; ni < 4; ++ni)
            bfr[ni] = *(const short8*)&lB[(wn + ni * 16 + lr) * 64 + xo];
        __builtin_amdgcn_s_setprio(1);
#pragma unroll
        for (int mi = 0; mi < 4; ++mi)
#pragma unroll
            for (int ni = 0; ni < 4; ++ni)
                acc[mi][ni] = mfma16(afr[mi], bfr[ni], acc[mi][ni]);
        __builtin_amdgcn_s_setprio(0);
    }
}

__device__ __forceinline__ void gemm_write(float* __restrict__ C, floatx4 (*acc)[4],
                                           int m0, int n0, int N, int lane, int wave) {
    int wm = (wave >> 1) * 64, wn = (wave & 1) * 64;
    int lr = lane & 15, lq = lane >> 4;
#pragma unroll
    for (int mi = 0; mi < 4; ++mi)
#pragma unroll
        for (int ni = 0; ni < 4; ++ni)
#pragma unroll
            for (int r = 0; r < 4; ++r)
                C[(size_t)(m0 + wm + mi * 16 + lq * 4 + r) * N + n0 + wn + ni * 16 + lr]
                    = acc[mi][ni][r];
}

// RoPE epilogue: rotate adjacent-column lane pairs, write bf16 [bh][s][64].
// K role (qlast != null): also fp32 last-token logits -> per-16-tile maxima -> tscores.
__device__ __forceinline__ void rope_epilogue(floatx4 (*acc)[4], int m0, int n0,
                                              const float* __restrict__ cost,
                                              const float* __restrict__ sint,
                                              const float* __restrict__ qlast,
                                              u16* __restrict__ dstb,
                                              float* __restrict__ tscores,
                                              int lane, int wave) {
    int wm = (wave >> 1) * 64, wn = (wave & 1) * 64;
    int lr = lane & 15, lq = lane >> 4;
    int odd = lr & 1;
    int h = (n0 + wn) >> 6;
    int bq = m0 >> 11;
    int s0 = m0 & 2047;
    float qr[4];
    if (qlast) {
#pragma unroll
        for (int ni = 0; ni < 4; ++ni) {
            int d = ni * 16 + lr;
            int i = d >> 1;
            float qv = qlast[(size_t)bq * E_ + h * 64 + d];
            float qp = __shfl_xor(qv, 1);
            float c = cost[2047 * 32 + i], sn = sint[2047 * 32 + i];
            qr[ni] = odd ? (qp * sn + qv * c) : (qv * c - qp * sn);
        }
    }
    float dotp[4][4];
#pragma unroll
    for (int mi = 0; mi < 4; ++mi)
#pragma unroll
        for (int r = 0; r < 4; ++r) dotp[mi][r] = 0.f;
#pragma unroll
    for (int ni = 0; ni < 4; ++ni) {
        int d = ni * 16 + lr;
        int i = d >> 1;
#pragma unroll
        for (int mi = 0; mi < 4; ++mi) {
#pragma unroll
            for (int r = 0; r < 4; ++r) {
                int row = m0 + wm + mi * 16 + lq * 4 + r;
                int s = row & 2047;
                float own = acc[mi][ni][r];
                float par = __shfl_xor(own, 1);
                float c = cost[s * 32 + i], sn = sint[s * 32 + i];
                float out = odd ? (par * sn + own * c) : (own * c - par * sn);
                dstb[(((size_t)(bq * 16 + h)) * S_ + s) * 64 + d] = f2bf(out);
                if (qlast) dotp[mi][r] += out * qr[ni];
            }
        }
    }
    if (qlast) {
#pragma unroll
        for (int mi = 0; mi < 4; ++mi) {
            float tm = -1e30f;
#pragma unroll
            for (int r = 0; r < 4; ++r) {
                float dv = dotp[mi][r];
                dv += __shfl_xor(dv, 1);
                dv += __shfl_xor(dv, 2);
                dv += __shfl_xor(dv, 4);
                dv += __shfl_xor(dv, 8);
                tm = fmaxf(tm, dv);
            }
            tm = fmaxf(tm, __shfl_xor(tm, 16));
            tm = fmaxf(tm, __shfl_xor(tm, 32));
            if (lane == 0)
                tscores[(size_t)(bq * 16 + h) * 128 + (s0 >> 4) + (wm >> 4) + mi] = tm;
        }
    }
}

// V epilogue: LDS-bounce transpose -> vtb [bh][d][s] bf16 (pad-136 rows)
__device__ __forceinline__ void v_epilogue(floatx4 (*acc)[4], int m0, int n0,
                                           u16* vt, u16* __restrict__ vtb,
                                           int lane, int wave, int tid) {
    int wm = (wave >> 1) * 64, wn = (wave & 1) * 64;
    int lr = lane & 15, lq = lane >> 4;
#pragma unroll
    for (int ni = 0; ni < 4; ++ni) {
        int dcol = wn + ni * 16 + lr;
#pragma unroll
        for (int mi = 0; mi < 4; ++mi)
#pragma unroll
            for (int r = 0; r < 4; ++r)
                vt[dcol * 136 + wm + mi * 16 + lq * 4 + r] = f2bf(acc[mi][ni][r]);
    }
    __syncthreads();
    int dcol = tid >> 1, sh = (tid & 1) * 64;
    int colg = n0 + dcol, h = colg >> 6, d = colg & 63;
    int bq = m0 >> 11, s0 = m0 & 2047;
    size_t base = (((size_t)(bq * 16 + h)) * 64 + d) * S_ + s0 + sh;
#pragma unroll
    for (int c = 0; c < 8; ++c)
        *(uint4*)&vtb[base + c * 8] = *(const uint4*)&vt[dcol * 136 + sh + c * 8];
}

// fused projections (R9 structure: 34.8KB LDS, 4 blocks/CU): 768 blocks, m-strips
// pinned per XCD. role 0: K (two loops, single accumulator) -> rope -> kb + tscores.
// role 1: Q -> rope -> qb. role 2: V -> vtb^T.
__global__ __launch_bounds__(256) void proj_gemm_kernel(const u16* __restrict__ xcat,
                                                        const u16* __restrict__ wqt,
                                                        const u16* __restrict__ wkt,
                                                        const u16* __restrict__ wkres,
                                                        const u16* __restrict__ wvt,
                                                        const float* __restrict__ cost,
                                                        const float* __restrict__ sint,
                                                        const float* __restrict__ qlast,
                                                        u16* __restrict__ qb,
                                                        u16* __restrict__ kb,
                                                        float* __restrict__ tscores,
                                                        u16* __restrict__ vtb) {
    __shared__ __align__(16) u16 lsbuf[17408];   // lA + lB; aliased as vt[128][136]
    u16* lA = lsbuf;
    u16* lB = lsbuf + 8192;
    int bx = blockIdx.x;
    int role = bx >> 8;                          // K first (longest)
    int idx = bx & 255;
    int xcd = idx & 7, loc = idx >> 3;
    int m0 = (xcd * 4 + (loc & 3)) * 128;        // m-strips pinned per XCD (L2-resident A)
    int n0 = (loc >> 2) * 128;
    int tid = threadIdx.x, lane = tid & 63, wave = tid >> 6;

    floatx4 acc[4][4];
#pragma unroll
    for (int i = 0; i < 4; ++i)
#pragma unroll
        for (int j = 0; j < 4; ++j) acc[i][j] = (floatx4){0.f, 0.f, 0.f, 0.f};

    if (role == 0) {
        for (int k0 = 0; k0 < 1024; k0 += 64) {
            stage_swz(xcat, m0, k0, 2048, lA, tid);
            stage_swz(wkt, n0, k0, 1024, lB, tid);
            __syncthreads();
            gemm_body(lA, lB, acc, lane, wave);
            __syncthreads();
        }
        for (int k0 = 0; k0 < 2048; k0 += 64) {
            stage_swz(xcat, m0, k0, 2048, lA, tid);
            stage_swz(wkres, n0, k0, 2048, lB, tid);
            __syncthreads();
            gemm_body(lA, lB, acc, lane, wave);
            __syncthreads();
        }
        rope_epilogue(acc, m0, n0, cost, sint, qlast, kb, tscores, lane, wave);
    } else if (role == 1) {
        for (int k0 = 0; k0 < 1024; k0 += 64) {
            stage_swz(xcat, m0, k0, 2048, lA, tid);
            stage_swz(wqt, n0, k0, 1024, lB, tid);
            __syncthreads();
            gemm_body(lA, lB, acc, lane, wave);
            __syncthreads();
        }
        rope_epilogue(acc, m0, n0, cost, sint, (const float*)nullptr, qb,
                      (float*)nullptr, lane, wave);
    } else {
        for (int k0 = 0; k0 < 1024; k0 += 64) {
            stage_swz(xcat, m0, k0, 2048, lA, tid);
            stage_swz(wvt, n0, k0, 1024, lB, tid);
            __syncthreads();
            gemm_body(lA, lB, acc, lane, wave);
            __syncthreads();
        }
        v_epilogue(acc, m0, n0, lsbuf, vtb, lane, wave, tid);
    }
}

// output projection GEMM, dbuf 2-phase (1 block/CU -> dbuf pays): C = A @ Bt^T
__global__ __launch_bounds__(256) void gemm_bf16_kernel(const u16* __restrict__ A,
                                                        const u16* __restrict__ Bt,
                                                        float* __restrict__ C,
                                                        int M, int N, int Kd) {
    __shared__ __align__(16) u16 lds4[4 * 8192];
    u16* T0 = lds4;
    u16* T1 = lds4 + 8192;
    u16* T2 = lds4 + 16384;
    u16* T3 = lds4 + 24576;
    int nwg = (M / 128) * (N / 128);
    int bx = blockIdx.x;
    int q = nwg >> 3, rr = nwg & 7, xcd = bx & 7, pos = bx >> 3;
    int lbx = (xcd < rr ? xcd * (q + 1) : rr * (q + 1) + (xcd - rr) * q) + pos;
    int nbn = N / 128;
    int m0 = (lbx / nbn) * 128, n0 = (lbx % nbn) * 128;
    int tid = threadIdx.x, lane = tid & 63, wave = tid >> 6;

    floatx4 acc[4][4];
#pragma unroll
    for (int i = 0; i < 4; ++i)
#pragma unroll
        for (int j = 0; j < 4; ++j) acc[i][j] = (floatx4){0.f, 0.f, 0.f, 0.f};

    int nsteps = Kd / 64;
    stage_swz(A, m0, 0, Kd, T0, tid);
    stage_swz(Bt, n0, 0, Kd, T2, tid);
    asm volatile("s_waitcnt vmcnt(0)" ::: "memory");
    __syncthreads();
    for (int step = 0; step < nsteps; ++step) {
        int buf = step & 1;
        u16* Ac = buf ? T1 : T0;
        u16* Bc = buf ? T3 : T2;
        if (step + 1 < nsteps) {
            stage_swz(A, m0, (step + 1) * 64, Kd, buf ? T0 : T1, tid);
            stage_swz(Bt, n0, (step + 1) * 64, Kd, buf ? T2 : T3, tid);
        }
        gemm_body(Ac, Bc, acc, lane, wave);
        asm volatile("s_waitcnt vmcnt(0)" ::: "memory");
        __syncthreads();
    }
    gemm_write(C, acc, m0, n0, N, lane, wave);
}

// ---------------- flash attention: QBLK=128 (two 16-row sub-tiles per wave) ----------------
__device__ __forceinline__ void stage_kv(const u16* __restrict__ K, const u16* __restrict__ V,
                                         int n0, u16* kbuf, u16* vbuf, int wave, int lane) {
    int lr = lane & 15, lq = lane >> 4;
    if (wave < 2) {
#pragma unroll
        for (int i = 0; i < 4; ++i) {
            int sk = wave * 4 + i;            // seg = kt*2 + kh
            int kt = sk >> 1, kh = (sk & 1) * 32;
            gload_lds16(&K[(size_t)(n0 + kt * 16 + lr) * D_ + kh + lq * 8],
                        kbuf + sk * 512);
        }
    } else {
#pragma unroll
        for (int i = 0; i < 4; ++i) {
            int sv = (wave - 2) * 4 + i;      // seg = c*4 + o
            int c = sv >> 2, o = sv & 3;
            gload_lds16(&V[(size_t)(o * 16 + lr) * S_ + n0 + c * 32 + lq * 8],
                        vbuf + sv * 512);
        }
    }
}

// softmax for one 16-row sub-tile; rows = qbase + lr (stats), o rows = qbase + lq*4 + r
__device__ __forceinline__ void softmax_tile(floatx4* st, int n0, int qbase,
                                             float& m, float& l, floatx4* o,
                                             u16* lp, int lr, int lq) {
    const float SC = 0.18033688011112042f;   // 0.125 * log2(e)
    int rem = qbase + 16 - n0;
    float sv[4][4];
    float bmax = -1e30f;
    if (rem >= 80) {                          // interior: causal always satisfied
#pragma unroll
        for (int kt = 0; kt < 4; ++kt)
#pragma unroll
            for (int r = 0; r < 4; ++r) {
                float s = st[kt][r] * SC;
                sv[kt][r] = s;
                bmax = fmaxf(bmax, s);
            }
    } else {
#pragma unroll
        for (int kt = 0; kt < 4; ++kt)
#pragma unroll
            for (int r = 0; r < 4; ++r) {
                int k = n0 + kt * 16 + lq * 4 + r;
                float s = (k <= qbase + lr) ? st[kt][r] * SC : -1e30f;
                sv[kt][r] = s;
                bmax = fmaxf(bmax, s);
            }
    }
    bmax = fmaxf(bmax, __shfl_xor(bmax, 16));
    bmax = fmaxf(bmax, __shfl_xor(bmax, 32));
    if (!__all(bmax <= m + 8.0f)) {           // defer-max (T13)
        float mn = fmaxf(m, bmax);
        float alpha = __builtin_amdgcn_exp2f(m - mn);
        m = mn;
        l *= alpha;
        float af[4];
#pragma unroll
        for (int r = 0; r < 4; ++r) af[r] = __shfl(alpha, lq * 4 + r);
#pragma unroll
        for (int r = 0; r < 4; ++r) {
            o[0][r] *= af[r]; o[1][r] *= af[r]; o[2][r] *= af[r]; o[3][r] *= af[r];
        }
    }
    float ps = 0.f;
#pragma unroll
    for (int kt = 0; kt < 4; ++kt) {
        float p0 = __builtin_amdgcn_exp2f(sv[kt][0] - m);
        float p1 = __builtin_amdgcn_exp2f(sv[kt][1] - m);
        float p2 = __builtin_amdgcn_exp2f(sv[kt][2] - m);
        float p3 = __builtin_amdgcn_exp2f(sv[kt][3] - m);
        ps += (p0 + p1) + (p2 + p3);
        unsigned wlo, whi;
        asm("v_cvt_pk_bf16_f32 %0, %1, %2" : "=v"(wlo) : "v"(p0), "v"(p1));
        asm("v_cvt_pk_bf16_f32 %0, %1, %2" : "=v"(whi) : "v"(p2), "v"(p3));
        *(uint2*)&lp[lr * PSTR + kt * 16 + lq * 4] = (uint2){wlo, whi};
    }
    ps += __shfl_xor(ps, 16);
    ps += __shfl_xor(ps, 32);
    l += ps;
}

__device__ __forceinline__ void pv_tile(const u16* lp, const short8 (*vv)[4],
                                        floatx4* o, int lr, int lk) {
#pragma unroll
    for (int c = 0; c < 2; ++c) {
        uint2 plo = *(const uint2*)&lp[lr * PSTR + c * 32 + lk];
        uint2 phi = *(const uint2*)&lp[lr * PSTR + c * 32 + lk + 4];
        short8 pfr = __builtin_bit_cast(short8, (uint4){plo.x, plo.y, phi.x, phi.y});
        o[0] = mfma16(pfr, vv[c][0], o[0]);
        o[1] = mfma16(pfr, vv[c][1], o[1]);
        o[2] = mfma16(pfr, vv[c][2], o[2]);
        o[3] = mfma16(pfr, vv[c][3], o[3]);
    }
}

__global__ __launch_bounds__(256, 2) void flash_kernel(const u16* __restrict__ qb,
                                                       const u16* __restrict__ kb,
                                                       const u16* __restrict__ vtb,
                                                       u16* __restrict__ ab) {
    __shared__ __align__(16) u16 kls[2][8 * 512];
    __shared__ __align__(16) u16 vls[2][8 * 512];
    __shared__ __align__(16) u16 ldsP[4][2][16 * PSTR];   // per-wave, per-sub-tile
    int tid = threadIdx.x;
    int lane = tid & 63, wave = tid >> 6;
    int bx = blockIdx.x;            // 512 blocks: 8 xcd x (4 heads x 16 chunks)
    int xcd = bx & 7, ii = bx >> 3;
    int hid = xcd + 8 * (ii & 3);   // 4 heads per XCD -> K/V L2-resident
    int qc = 15 - (ii >> 2);        // 128-row chunk; longest dispatch first
    int qt0 = qc * 128 + wave * 32; // wave's rows: A = qt0..+15, B = qt0+16..+31
    const u16* Q = qb + (size_t)hid * S_ * D_;
    const u16* K = kb + (size_t)hid * S_ * D_;
    const u16* V = vtb + (size_t)hid * D_ * S_;
    u16* lpA = &ldsP[wave][0][0];
    u16* lpB = &ldsP[wave][1][0];
    int lr = lane & 15, lq = lane >> 4, lk = lq * 8;

    short8 qfrA0 = *(const short8*)&Q[(size_t)(qt0 + lr) * D_ + lk];
    short8 qfrA1 = *(const short8*)&Q[(size_t)(qt0 + lr) * D_ + 32 + lk];
    short8 qfrB0 = *(const short8*)&Q[(size_t)(qt0 + 16 + lr) * D_ + lk];
    short8 qfrB1 = *(const short8*)&Q[(size_t)(qt0 + 16 + lr) * D_ + 32 + lk];

    floatx4 oA[4] = {{0,0,0,0},{0,0,0,0},{0,0,0,0},{0,0,0,0}};
    floatx4 oB[4] = {{0,0,0,0},{0,0,0,0},{0,0,0,0},{0,0,0,0}};
    float mA = -1e30f, lA_ = 0.f, mB = -1e30f, lB_ = 0.f;

    stage_kv(K, V, 0, kls[0], vls[0], wave, lane);
    asm volatile("s_waitcnt vmcnt(0)" ::: "memory");
    __syncthreads();

    int ntiles = 2 * qc + 2;
    for (int it = 0; it < ntiles; ++it) {
        int n0 = it * 64;
        int buf = it & 1;
        const u16* kbuf = kls[buf];
        const u16* vbuf = vls[buf];
        if (it + 1 < ntiles)
            stage_kv(K, V, n0 + 64, kls[buf ^ 1], vls[buf ^ 1], wave, lane);

        short8 ka0[4], ka1[4];
#pragma unroll
        for (int kt = 0; kt < 4; ++kt) {
            ka0[kt] = *(const short8*)&kbuf[(kt * 2 + 0) * 512 + lane * 8];
            ka1[kt] = *(const short8*)&kbuf[(kt * 2 + 1) * 512 + lane * 8];
        }
        floatx4 stA[4] = {{0,0,0,0},{0,0,0,0},{0,0,0,0},{0,0,0,0}};
        floatx4 stB[4] = {{0,0,0,0},{0,0,0,0},{0,0,0,0},{0,0,0,0}};
        __builtin_amdgcn_s_setprio(1);
#pragma unroll
        for (int kt = 0; kt < 4; ++kt) {
            stA[kt] = mfma16(ka0[kt], qfrA0, stA[kt]);
            stA[kt] = mfma16(ka1[kt], qfrA1, stA[kt]);
        }
#pragma unroll
        for (int kt = 0; kt < 4; ++kt) {
            stB[kt] = mfma16(ka0[kt], qfrB0, stB[kt]);
            stB[kt] = mfma16(ka1[kt], qfrB1, stB[kt]);
        }
        __builtin_amdgcn_s_setprio(0);

        softmax_tile(stA, n0, qt0, mA, lA_, oA, lpA, lr, lq);
        softmax_tile(stB, n0, qt0 + 16, mB, lB_, oB, lpB, lr, lq);

        short8 vv[2][4];
#pragma unroll
        for (int c = 0; c < 2; ++c)
#pragma unroll
            for (int o = 0; o < 4; ++o)
                vv[c][o] = *(const short8*)&vbuf[(c * 4 + o) * 512 + lane * 8];
        asm volatile("s_waitcnt lgkmcnt(0)" ::: "memory");
        __builtin_amdgcn_s_setprio(1);
        pv_tile(lpA, vv, oA, lr, lk);
        pv_tile(lpB, vv, oB, lr, lk);
        __builtin_amdgcn_s_setprio(0);

        if (it + 1 < ntiles) {
            asm volatile("s_waitcnt vmcnt(0)" ::: "memory");
            __syncthreads();
        }
    }
    int b = hid >> 4, h = hid & 15;
    {
        float li[4];
#pragma unroll
        for (int r = 0; r < 4; ++r) li[r] = 1.0f / __shfl(lA_, lq * 4 + r);
        size_t orow_base = ((size_t)b * S_ + qt0 + lq * 4) * E_ + h * D_;
#pragma unroll
        for (int r = 0; r < 4; ++r) {
            size_t rb = orow_base + (size_t)r * E_;
            ab[rb + 0  + lr] = f2bf(oA[0][r] * li[r]);
            ab[rb + 16 + lr] = f2bf(oA[1][r] * li[r]);
            ab[rb + 32 + lr] = f2bf(oA[2][r] * li[r]);
            ab[rb + 48 + lr] = f2bf(oA[3][r] * li[r]);
        }
    }
    {
        float li[4];
#pragma unroll
        for (int r = 0; r < 4; ++r) li[r] = 1.0f / __shfl(lB_, lq * 4 + r);
        size_t orow_base = ((size_t)b * S_ + qt0 + 16 + lq * 4) * E_ + h * D_;
#pragma unroll
        for (int r = 0; r < 4; ++r) {
            size_t rb = orow_base + (size_t)r * E_;
            ab[rb + 0  + lr] = f2bf(oB[0][r] * li[r]);
            ab[rb + 16 + lr] = f2bf(oB[1][r] * li[r]);
            ab[rb + 32 + lr] = f2bf(oB[2][r] * li[r]);
            ab[rb + 48 + lr] = f2bf(oB[3][r] * li[r]);
        }
    }
}

// ---------------- top-8 select from precomputed tile scores ----------------
__global__ __launch_bounds__(64) void topk_select_kernel(const float* __restrict__ tscores,
                                                         float* __restrict__ oidx) {
    int bh = blockIdx.x, tid = threadIdx.x;
    float v0 = tscores[bh * 128 + tid], v1 = tscores[bh * 128 + 64 + tid];
    float va, vb; int ia, ib;
    if (v1 > v0) { va = v1; ia = tid + 64; vb = v0; ib = tid; }
    else         { va = v0; ia = tid;      vb = v1; ib = tid + 64; }
    float cv = va; int ci = ia; int used = 0;
    for (int t = 0; t < 8; ++t) {
        float bv = cv; int bi = ci;
#pragma unroll
        for (int mk = 1; mk < 64; mk <<= 1) {
            float ov = __shfl_xor(bv, mk);
            int oi = __shfl_xor(bi, mk);
            if (ov > bv || (ov == bv && oi < bi)) { bv = ov; bi = oi; }
        }
        if (tid == 0) oidx[bh * 8 + t] = (float)bi;
        if (ci == bi) {
            if (used == 0) { cv = vb; ci = ib; used = 1; }
            else           { cv = -3e30f; ci = 1 << 20; }
        }
    }
}

// ---------------- launch ----------------
extern "C" void kernel_launch(void* const* d_in, const int* in_sizes, int n_in,
                              void* d_out, int out_size, void* d_ws, size_t ws_size,
                              hipStream_t stream) {
    (void)in_sizes; (void)n_in; (void)out_size; (void)ws_size;
    const float* x  = (const float*)d_in[0];
    const float* wq = (const float*)d_in[1];
    const float* wk = (const float*)d_in[2];
    const float* wv = (const float*)d_in[3];
    const float* wo = (const float*)d_in[4];
    float* out = (float*)d_out;

    char* wsp = (char*)d_ws;
    size_t off = 0;
    auto nxt = [&](size_t bytes) {
        char* p = wsp + off;
        off = (off + bytes + 255) & ~(size_t)255;
        return p;
    };
    u16* xcat  = (u16*)nxt((size_t)BS_ * 2048 * 2);
    u16* wqt   = (u16*)nxt((size_t)E_ * E_ * 2);
    u16* wkt   = (u16*)nxt((size_t)E_ * E_ * 2);
    u16* wkres = (u16*)nxt((size_t)E_ * 2048 * 2);
    u16* wvt   = (u16*)nxt((size_t)E_ * E_ * 2);
    u16* wot   = (u16*)nxt((size_t)E_ * E_ * 2);
    float* cost = (float*)nxt((size_t)S_ * 32 * 4);
    float* sint = (float*)nxt((size_t)S_ * 32 * 4);
    u16* qb    = (u16*)nxt((size_t)B_ * H_ * S_ * D_ * 2);
    u16* kb    = (u16*)nxt((size_t)B_ * H_ * S_ * D_ * 2);
    u16* vtb   = (u16*)nxt((size_t)B_ * H_ * S_ * D_ * 2);
    u16* ab    = (u16*)nxt((size_t)BS_ * E_ * 2);
    float* qlast = (float*)nxt((size_t)B_ * E_ * 4);
    float* tscores = (float*)nxt((size_t)B_ * H_ * 128 * 4);

    // merged prep (convert_x + W transposes + rope table + qlast) in one launch
    hipLaunchKernelGGL(prep_kernel, dim3(8512), dim3(256), 0, stream,
                       x, wq, wk, wv, wo, xcat, wqt, wkt, wkres, wvt, wot,
                       cost, sint, qlast);

    // fused projections: RoPE + V-transpose + top-k tile scores in the epilogues
    hipLaunchKernelGGL(proj_gemm_kernel, dim3(768), dim3(256), 0, stream,
                       xcat, wqt, wkt, wkres, wvt, cost, sint, qlast,
                       qb, kb, tscores, vtb);

    // attention (QBLK=128: 512 blocks)
    hipLaunchKernelGGL(flash_kernel, dim3(B_ * H_ * (S_ / 128)), dim3(256), 0, stream,
                       qb, kb, vtb, ab);

    // top-k select (tiny)
    hipLaunchKernelGGL(topk_select_kernel, dim3(B_ * H_), dim3(64), 0, stream,
                       tscores, out + (size_t)BS_ * E_);

    // output projection
    hipLaunchKernelGGL(gemm_bf16_kernel, dim3(256), dim3(256), 0, stream, ab, wot, out,
                       BS_, E_, E_);
}